// Round 1
// baseline (720.963 us; speedup 1.0000x reference)
//
#include <hip/hip_runtime.h>

// Per-edge Clebsch-Gordan tensor product:
//   out[i][p] = sum_{m,n} A[i][m] * B[i][n] * C[m][n][p]
// m1 = m2 = mL = 5. Memory-bound streaming kernel (ideal traffic ~1.0 GB).
//
// This version makes ALL global traffic perfectly coalesced:
//   global (coalesced 1KiB/instr, global_load_lds) -> LDS -> per-thread
//   80B fragments (conflict-free: stride 20 dwords tiles all 32 banks per
//   8-lane phase group) -> compute -> LDS -> coalesced float4 stores.
// Previous version used 80B-strided float4 accesses straight to HBM: every
// lane of every vmem instruction hit a distinct 64B line (4x transaction
// inflation + L1 thrash) -> ~20% of achievable HBM BW.

#define M1 5
#define M2 5
#define ML 5
#define EPT 4                       // edges per thread
#define BLOCK 256
#define EPB (BLOCK * EPT)           // 1024 edges per block
#define FLT_PER_WAVE 1280           // 64 threads * 4 edges * 5 floats
#define FLT_PER_BLOCK 5120          // 256 threads * 20 floats

typedef const __attribute__((address_space(1))) void* gas_ptr;
typedef __attribute__((address_space(3))) void* las_ptr;

__global__ __launch_bounds__(BLOCK, 4) void cg_combine_kernel(
    const float* __restrict__ A,
    const float* __restrict__ B,
    const float* __restrict__ C,
    float* __restrict__ out)
{
    __shared__ float ldsA[FLT_PER_BLOCK];
    __shared__ float ldsB[FLT_PER_BLOCK];

    const int tid  = threadIdx.x;
    const int w    = tid >> 6;      // wave id within block
    const int lane = tid & 63;

    const size_t blk = (size_t)blockIdx.x * FLT_PER_BLOCK;

    // ---- Stage A,B -> LDS, fully coalesced (1 KiB per wave per issue). ----
    // Wave w stages exactly its own threads' region [w*5120B, (w+1)*5120B):
    // LDS dest = uniform base + lane*16 (the HW-supported linear pattern).
    {
        const float* gA = A + blk + (size_t)w * FLT_PER_WAVE + lane * 4;
        const float* gB = B + blk + (size_t)w * FLT_PER_WAVE + lane * 4;
        float* lA = ldsA + w * FLT_PER_WAVE;   // wave-uniform
        float* lB = ldsB + w * FLT_PER_WAVE;   // wave-uniform
#pragma unroll
        for (int k = 0; k < 5; ++k) {
            __builtin_amdgcn_global_load_lds((gas_ptr)(gA + k * 256),
                                             (las_ptr)(lA + k * 256), 16, 0, 0);
            __builtin_amdgcn_global_load_lds((gas_ptr)(gB + k * 256),
                                             (las_ptr)(lB + k * 256), 16, 0, 0);
        }
    }
    __syncthreads();  // drains vmcnt -> staged data visible

    // ---- Per-thread fragment read: own 80 B, bank-conflict-free. ----
    float a[EPT * M1];
    float b[EPT * M2];
    {
        const float4* lA4 = (const float4*)ldsA + tid * 5;
        const float4* lB4 = (const float4*)ldsB + tid * 5;
#pragma unroll
        for (int k = 0; k < 5; ++k) {
            float4 va = lA4[k];
            float4 vb = lB4[k];
            a[4 * k + 0] = va.x; a[4 * k + 1] = va.y;
            a[4 * k + 2] = va.z; a[4 * k + 3] = va.w;
            b[4 * k + 0] = vb.x; b[4 * k + 1] = vb.y;
            b[4 * k + 2] = vb.z; b[4 * k + 3] = vb.w;
        }
    }

    float acc[EPT * ML];
#pragma unroll
    for (int i = 0; i < EPT * ML; ++i) acc[i] = 0.0f;

#pragma unroll
    for (int m = 0; m < M1; ++m) {
#pragma unroll
        for (int n = 0; n < M2; ++n) {
            float ab0 = a[0 * M1 + m] * b[0 * M2 + n];
            float ab1 = a[1 * M1 + m] * b[1 * M2 + n];
            float ab2 = a[2 * M1 + m] * b[2 * M2 + n];
            float ab3 = a[3 * M1 + m] * b[3 * M2 + n];
#pragma unroll
            for (int p = 0; p < ML; ++p) {
                float c = C[(m * M2 + n) * ML + p];  // wave-uniform -> s_load
                acc[0 * ML + p] = fmaf(ab0, c, acc[0 * ML + p]);
                acc[1 * ML + p] = fmaf(ab1, c, acc[1 * ML + p]);
                acc[2 * ML + p] = fmaf(ab2, c, acc[2 * ML + p]);
                acc[3 * ML + p] = fmaf(ab3, c, acc[3 * ML + p]);
            }
        }
    }

    // ---- Stage out through LDS (reuse ldsA: each thread touches only its
    // own region, so no barrier needed before the overwrite). ----
    {
        float4* lO4 = (float4*)ldsA + tid * 5;
#pragma unroll
        for (int k = 0; k < 5; ++k) {
            float4 vo;
            vo.x = acc[4 * k + 0]; vo.y = acc[4 * k + 1];
            vo.z = acc[4 * k + 2]; vo.w = acc[4 * k + 3];
            lO4[k] = vo;
        }
    }
    __syncthreads();

    // ---- Coalesced float4 stores (1 KiB per wave per instruction). ----
    {
        const float4* lO4 = (const float4*)(ldsA + w * FLT_PER_WAVE);
        float4* gO4 = (float4*)(out + blk + (size_t)w * FLT_PER_WAVE);
#pragma unroll
        for (int k = 0; k < 5; ++k) {
            gO4[k * 64 + lane] = lO4[k * 64 + lane];
        }
    }
}

// Tail path (scalar, 1 edge per thread) for n_edges % EPB != 0.
__global__ void cg_combine_tail_kernel(
    const float* __restrict__ A,
    const float* __restrict__ B,
    const float* __restrict__ C,
    float* __restrict__ out,
    int start_edge, int n_edges)
{
    int i = start_edge + blockIdx.x * blockDim.x + threadIdx.x;
    if (i >= n_edges) return;

    float a[M1], b[M2];
#pragma unroll
    for (int m = 0; m < M1; ++m) a[m] = A[(size_t)i * M1 + m];
#pragma unroll
    for (int n = 0; n < M2; ++n) b[n] = B[(size_t)i * M2 + n];

    float acc[ML];
#pragma unroll
    for (int p = 0; p < ML; ++p) acc[p] = 0.0f;

#pragma unroll
    for (int m = 0; m < M1; ++m) {
#pragma unroll
        for (int n = 0; n < M2; ++n) {
            float ab = a[m] * b[n];
#pragma unroll
            for (int p = 0; p < ML; ++p)
                acc[p] = fmaf(ab, C[(m * M2 + n) * ML + p], acc[p]);
        }
    }

#pragma unroll
    for (int p = 0; p < ML; ++p) out[(size_t)i * ML + p] = acc[p];
}

extern "C" void kernel_launch(void* const* d_in, const int* in_sizes, int n_in,
                              void* d_out, int out_size, void* d_ws, size_t ws_size,
                              hipStream_t stream) {
    const float* A = (const float*)d_in[0];
    const float* B = (const float*)d_in[1];
    const float* C = (const float*)d_in[2];
    float* out = (float*)d_out;

    const int n_edges  = in_sizes[0] / M1;       // 16,777,216
    const int n_blocks = n_edges / EPB;          // 16,384 full blocks
    const int done     = n_blocks * EPB;

    if (n_blocks > 0) {
        cg_combine_kernel<<<n_blocks, BLOCK, 0, stream>>>(A, B, C, out);
    }
    if (done < n_edges) {
        const int rem = n_edges - done;
        const int tb  = (rem + 255) / 256;
        cg_combine_tail_kernel<<<tb, 256, 0, stream>>>(A, B, C, out, done, n_edges);
    }
}